// Round 4
// baseline (267.881 us; speedup 1.0000x reference)
//
#include <hip/hip_runtime.h>
#include <math.h>

#define EPS 1e-8f
#define BS 128
#define W 256
#define N 2048
#define R 4

__device__ inline float wave_sum(float v) {
#pragma unroll
    for (int o = 32; o > 0; o >>= 1) v += __shfl_xor(v, o, 64);
    return v;
}
__device__ inline float wave_max(float v) {
#pragma unroll
    for (int o = 32; o > 0; o >>= 1) v = fmaxf(v, __shfl_xor(v, o, 64));
    return v;
}

// ---------------------------------------------------------------------------
// Kernel 1: per-batch prep. block = 256 (= W), grid = BS.
// ---------------------------------------------------------------------------
__global__ void k_prep(const float* __restrict__ k_r, const float* __restrict__ m_t,
                       const float* __restrict__ e_t, const float* __restrict__ m_er,
                       const float* __restrict__ gW, const float* __restrict__ gb,
                       const float* __restrict__ oW, const float* __restrict__ ob,
                       float* __restrict__ wm_o, float* __restrict__ er_o,
                       float* __restrict__ knw_o, float* __restrict__ knr_o) {
    int b = blockIdx.x, t = threadIdx.x;
    int lane = t & 63, wid = t >> 6;
    __shared__ float red[4];
    __shared__ float gated[2 * W];
    __shared__ float wk_s[W];

    float wm = tanhf(m_t[b * W + t]);
    float me = m_er[b * W + t];
    wm_o[b * W + t] = wm;

    // erase softmax over W
    float e = e_t[b * W + t];
    float mx = wave_max(e);
    if (lane == 0) red[wid] = mx;
    __syncthreads();
    mx = fmaxf(fmaxf(red[0], red[1]), fmaxf(red[2], red[3]));
    __syncthreads();
    float ex = expf(e - mx);
    float s = wave_sum(ex);
    if (lane == 0) red[wid] = s;
    __syncthreads();
    s = red[0] + red[1] + red[2] + red[3];
    __syncthreads();
    er_o[b * W + t] = ex / s;

    // MixGate scalar g
    float p = wm * gW[t] + me * gW[W + t];
    float ps = wave_sum(p);
    if (lane == 0) red[wid] = ps;
    __syncthreads();
    ps = red[0] + red[1] + red[2] + red[3] + gb[0];
    __syncthreads();
    float g = 1.0f / (1.0f + expf(-ps));
    gated[t] = g * wm;
    gated[W + t] = (1.0f - g) * me;
    __syncthreads();

    // write_key: wave wid computes rows o = wid*64 + i (coalesced float4)
    const float4* g4 = (const float4*)gated;
    float4 g0 = g4[lane];
    float4 g1 = g4[64 + lane];
    for (int i = 0; i < 64; i++) {
        int o = wid * 64 + i;
        const float4* orow = (const float4*)(oW + (size_t)o * 2 * W);
        float4 w0 = orow[lane];
        float4 w1 = orow[64 + lane];
        float pp = w0.x * g0.x + w0.y * g0.y + w0.z * g0.z + w0.w * g0.w
                 + w1.x * g1.x + w1.y * g1.y + w1.z * g1.z + w1.w * g1.w;
        pp = wave_sum(pp);
        if (lane == 0) wk_s[o] = fmaxf(pp + ob[o], 0.0f);
    }
    __syncthreads();
    float wk = wk_s[t];
    float ss = wave_sum(wk * wk);
    if (lane == 0) red[wid] = ss;
    __syncthreads();
    ss = red[0] + red[1] + red[2] + red[3];
    __syncthreads();
    knw_o[b * W + t] = wk / (sqrtf(ss) + EPS);

    // normalized read keys
    for (int r = 0; r < R; r++) {
        float rk = tanhf(k_r[(b * R + r) * W + t]);
        float s2 = wave_sum(rk * rk);
        if (lane == 0) red[wid] = s2;
        __syncthreads();
        s2 = red[0] + red[1] + red[2] + red[3];
        __syncthreads();
        knr_o[(b * R + r) * W + t] = rk / (sqrtf(s2) + EPS);
    }
}

// ---------------------------------------------------------------------------
// Kernel 2: write-direction cosine distances (negated), raw (pre-softmax).
// w-range split in half across thread halves: grid (4, BS), block 256,
// thread (half = t>>7, c = t&127) covers f4-col blockIdx.x*128+c for 128 w's.
// 512 blocks = 2 blocks/CU = 8 waves/CU; unroll 8 -> 64 KB/CU in flight.
// ---------------------------------------------------------------------------
__global__ void __launch_bounds__(256, 2)
k_wdist(const float* __restrict__ mem, const float* __restrict__ knw,
        float* __restrict__ dist) {
    int b = blockIdx.y;
    int t = threadIdx.x;
    int half = t >> 7, c = t & 127;
    int n4 = blockIdx.x * 128 + c;
    __shared__ float k[W];
    __shared__ float4 pdot[128], pss[128];
    k[t] = knw[b * W + t];
    __syncthreads();
    const float4* base = (const float4*)(mem + (size_t)b * W * N) + n4;
    float4 dot = make_float4(0.f, 0.f, 0.f, 0.f);
    float4 ss = make_float4(0.f, 0.f, 0.f, 0.f);
    int w0 = half * 128;
#pragma unroll 8
    for (int i = 0; i < 128; i++) {
        int w = w0 + i;
        float4 v = base[(size_t)w * (N / 4)];
        float kw = k[w];
        dot.x += kw * v.x; dot.y += kw * v.y; dot.z += kw * v.z; dot.w += kw * v.w;
        ss.x += v.x * v.x; ss.y += v.y * v.y; ss.z += v.z * v.z; ss.w += v.w * v.w;
    }
    if (half == 0) { pdot[c] = dot; pss[c] = ss; }
    __syncthreads();
    if (half == 1) {
        float4 od = pdot[c], os = pss[c];
        dot.x += od.x; dot.y += od.y; dot.z += od.z; dot.w += od.w;
        ss.x += os.x; ss.y += os.y; ss.z += os.z; ss.w += os.w;
        float4 o;
        o.x = -(dot.x / (sqrtf(ss.x) + EPS));
        o.y = -(dot.y / (sqrtf(ss.y) + EPS));
        o.z = -(dot.z / (sqrtf(ss.z) + EPS));
        o.w = -(dot.w / (sqrtf(ss.w) + EPS));
        ((float4*)(dist + (size_t)b * N))[n4] = o;
    }
}

// ---------------------------------------------------------------------------
// Kernel 3: in-place row softmax over N=2048 (for read_wt rows).
// ---------------------------------------------------------------------------
__global__ void k_softmax_rows(float* __restrict__ io) {
    int row = blockIdx.x, t = threadIdx.x;
    int lane = t & 63, wid = t >> 6;
    float* p = io + (size_t)row * N;
    __shared__ float red[4];
    float v[8];
    float mx = -INFINITY;
#pragma unroll
    for (int k = 0; k < 8; k++) {
        v[k] = p[t + k * 256];
        mx = fmaxf(mx, v[k]);
    }
    mx = wave_max(mx);
    if (lane == 0) red[wid] = mx;
    __syncthreads();
    mx = fmaxf(fmaxf(red[0], red[1]), fmaxf(red[2], red[3]));
    __syncthreads();
    float s = 0.f;
#pragma unroll
    for (int k = 0; k < 8; k++) {
        v[k] = expf(v[k] - mx);
        s += v[k];
    }
    s = wave_sum(s);
    if (lane == 0) red[wid] = s;
    __syncthreads();
    s = red[0] + red[1] + red[2] + red[3];
    float inv = 1.0f / s;
#pragma unroll
    for (int k = 0; k < 8; k++) p[t + k * 256] = v[k] * inv;
}

// ---------------------------------------------------------------------------
// Kernel 4: fused write-softmax + memory update + read-dist.
// Same half-split geometry as k_wdist: grid (4, BS), block 256.
// Prologue: block-redundant softmax over the raw 2048 dist row -> wt for
// this thread's f4-col. Main: per-half w-loop computes Mnew rows, partial
// column norms + 4 read-key dots; cross-half combine in LDS; half 1 writes
// raw dist_r.
// ---------------------------------------------------------------------------
__global__ void __launch_bounds__(256, 2)
k_update(const float* __restrict__ mem, const float* __restrict__ wdist,
         const float* __restrict__ er, const float* __restrict__ wm,
         const float* __restrict__ knr,
         float* __restrict__ Mnew, float* __restrict__ dist_r) {
    int b = blockIdx.y;
    int t = threadIdx.x;
    int lane = t & 63, wid = t >> 6;
    int half = t >> 7, c = t & 127;
    int n4 = blockIdx.x * 128 + c;
    __shared__ float se[W], sw[W];
    __shared__ float4 skT[W];
    __shared__ float red[4];
    __shared__ float4 pd0[128], pd1[128], pd2[128], pd3[128], pssv[128];
    se[t] = er[b * W + t];
    sw[t] = wm[b * W + t];
    const float* kb = knr + (size_t)b * R * W;
    skT[t] = make_float4(kb[t], kb[W + t], kb[2 * W + t], kb[3 * W + t]);

    // --- block-redundant softmax over the full raw dist row (2048) ---
    const float4* drow4 = (const float4*)(wdist + (size_t)b * N);
    float4 a0 = drow4[t];
    float4 a1 = drow4[256 + t];
    float mx = fmaxf(fmaxf(fmaxf(a0.x, a0.y), fmaxf(a0.z, a0.w)),
                     fmaxf(fmaxf(a1.x, a1.y), fmaxf(a1.z, a1.w)));
    mx = wave_max(mx);
    if (lane == 0) red[wid] = mx;
    __syncthreads();
    mx = fmaxf(fmaxf(red[0], red[1]), fmaxf(red[2], red[3]));
    __syncthreads();
    float sm = expf(a0.x - mx) + expf(a0.y - mx) + expf(a0.z - mx) + expf(a0.w - mx)
             + expf(a1.x - mx) + expf(a1.y - mx) + expf(a1.z - mx) + expf(a1.w - mx);
    sm = wave_sum(sm);
    if (lane == 0) red[wid] = sm;
    __syncthreads();
    sm = red[0] + red[1] + red[2] + red[3];
    float inv = 1.0f / sm;
    float4 dmine = drow4[n4];
    float4 wt;
    wt.x = expf(dmine.x - mx) * inv;
    wt.y = expf(dmine.y - mx) * inv;
    wt.z = expf(dmine.z - mx) * inv;
    wt.w = expf(dmine.w - mx) * inv;

    const float4* mb = (const float4*)(mem + (size_t)b * W * N) + n4;
    float4* ob = (float4*)(Mnew + (size_t)b * W * N) + n4;
    float4 ssv = make_float4(0.f, 0.f, 0.f, 0.f);
    float4 d0 = make_float4(0.f, 0.f, 0.f, 0.f);
    float4 d1 = make_float4(0.f, 0.f, 0.f, 0.f);
    float4 d2 = make_float4(0.f, 0.f, 0.f, 0.f);
    float4 d3 = make_float4(0.f, 0.f, 0.f, 0.f);
    int w0 = half * 128;
#pragma unroll 8
    for (int i = 0; i < 128; i++) {
        int w = w0 + i;
        float4 v = mb[(size_t)w * (N / 4)];
        float ew = se[w], mw = sw[w];
        float4 mn;
        mn.x = v.x + wt.x * (mw - v.x * ew);
        mn.y = v.y + wt.y * (mw - v.y * ew);
        mn.z = v.z + wt.z * (mw - v.z * ew);
        mn.w = v.w + wt.w * (mw - v.w * ew);
        ob[(size_t)w * (N / 4)] = mn;
        ssv.x += mn.x * mn.x; ssv.y += mn.y * mn.y;
        ssv.z += mn.z * mn.z; ssv.w += mn.w * mn.w;
        float4 kv = skT[w];
        d0.x += kv.x * mn.x; d0.y += kv.x * mn.y; d0.z += kv.x * mn.z; d0.w += kv.x * mn.w;
        d1.x += kv.y * mn.x; d1.y += kv.y * mn.y; d1.z += kv.y * mn.z; d1.w += kv.y * mn.w;
        d2.x += kv.z * mn.x; d2.y += kv.z * mn.y; d2.z += kv.z * mn.z; d2.w += kv.z * mn.w;
        d3.x += kv.w * mn.x; d3.y += kv.w * mn.y; d3.z += kv.w * mn.z; d3.w += kv.w * mn.w;
    }
    if (half == 0) {
        pd0[c] = d0; pd1[c] = d1; pd2[c] = d2; pd3[c] = d3; pssv[c] = ssv;
    }
    __syncthreads();
    if (half == 1) {
        float4 q;
        q = pd0[c]; d0.x += q.x; d0.y += q.y; d0.z += q.z; d0.w += q.w;
        q = pd1[c]; d1.x += q.x; d1.y += q.y; d1.z += q.z; d1.w += q.w;
        q = pd2[c]; d2.x += q.x; d2.y += q.y; d2.z += q.z; d2.w += q.w;
        q = pd3[c]; d3.x += q.x; d3.y += q.y; d3.z += q.z; d3.w += q.w;
        q = pssv[c]; ssv.x += q.x; ssv.y += q.y; ssv.z += q.z; ssv.w += q.w;
        float4 ivn;
        ivn.x = 1.0f / (sqrtf(ssv.x) + EPS);
        ivn.y = 1.0f / (sqrtf(ssv.y) + EPS);
        ivn.z = 1.0f / (sqrtf(ssv.z) + EPS);
        ivn.w = 1.0f / (sqrtf(ssv.w) + EPS);
        float4* dr = (float4*)(dist_r + (size_t)b * R * N);
        dr[0 * (N / 4) + n4] = make_float4(d0.x * ivn.x, d0.y * ivn.y, d0.z * ivn.z, d0.w * ivn.w);
        dr[1 * (N / 4) + n4] = make_float4(d1.x * ivn.x, d1.y * ivn.y, d1.z * ivn.z, d1.w * ivn.w);
        dr[2 * (N / 4) + n4] = make_float4(d2.x * ivn.x, d2.y * ivn.y, d2.z * ivn.z, d2.w * ivn.w);
        dr[3 * (N / 4) + n4] = make_float4(d3.x * ivn.x, d3.y * ivn.y, d3.z * ivn.z, d3.w * ivn.w);
    }
}

// ---------------------------------------------------------------------------
// Kernel 5: m_read[b,r,w] = sum_n read_wt[b,r,n] * M_new[b,w,n].
// grid (4, BS), block 256 (4 waves). Wave (rowgrp=wid>>1, half=wid&1):
// rows w0+rowgrp*32..+32, n in [half*1024, half*1024+1024).
// ---------------------------------------------------------------------------
__global__ void __launch_bounds__(256, 2)
k_mread(const float* __restrict__ Mnew, const float* __restrict__ rwt_g,
        float* __restrict__ m_read) {
    int b = blockIdx.y;
    int w0 = blockIdx.x * 64;
    int t = threadIdx.x;
    int lane = t & 63, wid = t >> 6;
    int half = wid & 1, rowgrp = wid >> 1;
    int fbase = half * 256 + lane;  // float4 index base within a row

    float4 rw[R][4];
#pragma unroll
    for (int r = 0; r < R; r++) {
        const float4* rrow = (const float4*)(rwt_g + ((size_t)b * R + r) * N);
#pragma unroll
        for (int k = 0; k < 4; k++) rw[r][k] = rrow[fbase + k * 64];
    }

    __shared__ float part[64][2][4];
    const float* Mb = Mnew + (size_t)b * W * N;
#pragma unroll 4
    for (int wi = 0; wi < 32; wi++) {
        int wl = rowgrp * 32 + wi;
        const float4* mrow = (const float4*)(Mb + (size_t)(w0 + wl) * N);
        float4 v[4];
#pragma unroll
        for (int k = 0; k < 4; k++) v[k] = mrow[fbase + k * 64];
        float a0 = 0.f, a1 = 0.f, a2 = 0.f, a3 = 0.f;
#pragma unroll
        for (int k = 0; k < 4; k++) {
            a0 += rw[0][k].x * v[k].x + rw[0][k].y * v[k].y + rw[0][k].z * v[k].z + rw[0][k].w * v[k].w;
            a1 += rw[1][k].x * v[k].x + rw[1][k].y * v[k].y + rw[1][k].z * v[k].z + rw[1][k].w * v[k].w;
            a2 += rw[2][k].x * v[k].x + rw[2][k].y * v[k].y + rw[2][k].z * v[k].z + rw[2][k].w * v[k].w;
            a3 += rw[3][k].x * v[k].x + rw[3][k].y * v[k].y + rw[3][k].z * v[k].z + rw[3][k].w * v[k].w;
        }
        a0 = wave_sum(a0);
        a1 = wave_sum(a1);
        a2 = wave_sum(a2);
        a3 = wave_sum(a3);
        if (lane == 0) {
            part[wl][half][0] = a0;
            part[wl][half][1] = a1;
            part[wl][half][2] = a2;
            part[wl][half][3] = a3;
        }
    }
    __syncthreads();
    int w = t >> 2, r = t & 3;
    float sres = part[w][0][r] + part[w][1][r];
    m_read[((size_t)b * R + r) * W + w0 + w] = sres;
}

extern "C" void kernel_launch(void* const* d_in, const int* in_sizes, int n_in,
                              void* d_out, int out_size, void* d_ws, size_t ws_size,
                              hipStream_t stream) {
    const float* k_r  = (const float*)d_in[0];
    const float* m_t  = (const float*)d_in[1];
    const float* e_t  = (const float*)d_in[2];
    const float* m_er = (const float*)d_in[3];
    const float* mem  = (const float*)d_in[4];
    const float* gW   = (const float*)d_in[5];
    const float* gb   = (const float*)d_in[6];
    const float* oW   = (const float*)d_in[7];
    const float* ob   = (const float*)d_in[8];

    float* out = (float*)d_out;
    // output layout: m_read (bs,R,W) | M_new (bs,W,N) | read_wt (bs,R,N)
    float* m_read = out;
    float* Mnew   = out + (size_t)BS * R * W;
    float* rwt    = out + (size_t)BS * R * W + (size_t)BS * W * N;

    float* ws  = (float*)d_ws;
    float* wm  = ws;                          // BS*W
    float* er  = ws + (size_t)BS * W;         // BS*W
    float* knw = ws + (size_t)2 * BS * W;     // BS*W
    float* knr = ws + (size_t)3 * BS * W;     // BS*R*W
    float* wdist = ws + (size_t)3 * BS * W + (size_t)BS * R * W;  // BS*N raw dist

    k_prep<<<BS, 256, 0, stream>>>(k_r, m_t, e_t, m_er, gW, gb, oW, ob, wm, er, knw, knr);
    k_wdist<<<dim3(4, BS), 256, 0, stream>>>(mem, knw, wdist);
    k_update<<<dim3(4, BS), 256, 0, stream>>>(mem, wdist, er, wm, knr, Mnew, rwt);
    k_softmax_rows<<<BS * R, 256, 0, stream>>>(rwt);  // raw dist_r -> read_wt
    k_mread<<<dim3(4, BS), 256, 0, stream>>>(Mnew, rwt, m_read);
}

// Round 5
// 250.419 us; speedup vs baseline: 1.0697x; 1.0697x over previous
//
#include <hip/hip_runtime.h>
#include <math.h>

#define EPS 1e-8f
#define BS 128
#define W 256
#define N 2048
#define R 4

using v4f = float __attribute__((ext_vector_type(4)));

__device__ inline float wave_sum(float v) {
#pragma unroll
    for (int o = 32; o > 0; o >>= 1) v += __shfl_xor(v, o, 64);
    return v;
}
__device__ inline float wave_max(float v) {
#pragma unroll
    for (int o = 32; o > 0; o >>= 1) v = fmaxf(v, __shfl_xor(v, o, 64));
    return v;
}

// ---------------------------------------------------------------------------
// Kernel 1: per-batch prep. block = 256 (= W), grid = BS.
// ---------------------------------------------------------------------------
__global__ void k_prep(const float* __restrict__ k_r, const float* __restrict__ m_t,
                       const float* __restrict__ e_t, const float* __restrict__ m_er,
                       const float* __restrict__ gW, const float* __restrict__ gb,
                       const float* __restrict__ oW, const float* __restrict__ ob,
                       float* __restrict__ wm_o, float* __restrict__ er_o,
                       float* __restrict__ knw_o, float* __restrict__ knr_o) {
    int b = blockIdx.x, t = threadIdx.x;
    int lane = t & 63, wid = t >> 6;
    __shared__ float red[4];
    __shared__ float gated[2 * W];
    __shared__ float wk_s[W];

    float wm = tanhf(m_t[b * W + t]);
    float me = m_er[b * W + t];
    wm_o[b * W + t] = wm;

    // erase softmax over W
    float e = e_t[b * W + t];
    float mx = wave_max(e);
    if (lane == 0) red[wid] = mx;
    __syncthreads();
    mx = fmaxf(fmaxf(red[0], red[1]), fmaxf(red[2], red[3]));
    __syncthreads();
    float ex = expf(e - mx);
    float s = wave_sum(ex);
    if (lane == 0) red[wid] = s;
    __syncthreads();
    s = red[0] + red[1] + red[2] + red[3];
    __syncthreads();
    er_o[b * W + t] = ex / s;

    // MixGate scalar g
    float p = wm * gW[t] + me * gW[W + t];
    float ps = wave_sum(p);
    if (lane == 0) red[wid] = ps;
    __syncthreads();
    ps = red[0] + red[1] + red[2] + red[3] + gb[0];
    __syncthreads();
    float g = 1.0f / (1.0f + expf(-ps));
    gated[t] = g * wm;
    gated[W + t] = (1.0f - g) * me;
    __syncthreads();

    // write_key: wave wid computes rows o = wid*64 + i (coalesced float4)
    const float4* g4 = (const float4*)gated;
    float4 g0 = g4[lane];
    float4 g1 = g4[64 + lane];
    for (int i = 0; i < 64; i++) {
        int o = wid * 64 + i;
        const float4* orow = (const float4*)(oW + (size_t)o * 2 * W);
        float4 w0 = orow[lane];
        float4 w1 = orow[64 + lane];
        float pp = w0.x * g0.x + w0.y * g0.y + w0.z * g0.z + w0.w * g0.w
                 + w1.x * g1.x + w1.y * g1.y + w1.z * g1.z + w1.w * g1.w;
        pp = wave_sum(pp);
        if (lane == 0) wk_s[o] = fmaxf(pp + ob[o], 0.0f);
    }
    __syncthreads();
    float wk = wk_s[t];
    float ss = wave_sum(wk * wk);
    if (lane == 0) red[wid] = ss;
    __syncthreads();
    ss = red[0] + red[1] + red[2] + red[3];
    __syncthreads();
    knw_o[b * W + t] = wk / (sqrtf(ss) + EPS);

    // normalized read keys
    for (int r = 0; r < R; r++) {
        float rk = tanhf(k_r[(b * R + r) * W + t]);
        float s2 = wave_sum(rk * rk);
        if (lane == 0) red[wid] = s2;
        __syncthreads();
        s2 = red[0] + red[1] + red[2] + red[3];
        __syncthreads();
        knr_o[(b * R + r) * W + t] = rk / (sqrtf(s2) + EPS);
    }
}

// ---------------------------------------------------------------------------
// Kernel 2: write-direction cosine distances (negated), raw (pre-softmax).
// grid (4, BS), block 256; (half = t>>7, c = t&127). Normal (temporal) loads
// of mem — we WANT mem resident in L3 for k_update's re-read.
// ---------------------------------------------------------------------------
__global__ void __launch_bounds__(256, 2)
k_wdist(const float* __restrict__ mem, const float* __restrict__ knw,
        float* __restrict__ dist) {
    int b = blockIdx.y;
    int t = threadIdx.x;
    int half = t >> 7, c = t & 127;
    int n4 = blockIdx.x * 128 + c;
    __shared__ float k[W];
    __shared__ float4 pdot[128], pss[128];
    k[t] = knw[b * W + t];
    __syncthreads();
    const float4* base = (const float4*)(mem + (size_t)b * W * N) + n4;
    float4 dot = make_float4(0.f, 0.f, 0.f, 0.f);
    float4 ss = make_float4(0.f, 0.f, 0.f, 0.f);
    int w0 = half * 128;
#pragma unroll 8
    for (int i = 0; i < 128; i++) {
        int w = w0 + i;
        float4 v = base[(size_t)w * (N / 4)];
        float kw = k[w];
        dot.x += kw * v.x; dot.y += kw * v.y; dot.z += kw * v.z; dot.w += kw * v.w;
        ss.x += v.x * v.x; ss.y += v.y * v.y; ss.z += v.z * v.z; ss.w += v.w * v.w;
    }
    if (half == 0) { pdot[c] = dot; pss[c] = ss; }
    __syncthreads();
    if (half == 1) {
        float4 od = pdot[c], os = pss[c];
        dot.x += od.x; dot.y += od.y; dot.z += od.z; dot.w += od.w;
        ss.x += os.x; ss.y += os.y; ss.z += os.z; ss.w += os.w;
        float4 o;
        o.x = -(dot.x / (sqrtf(ss.x) + EPS));
        o.y = -(dot.y / (sqrtf(ss.y) + EPS));
        o.z = -(dot.z / (sqrtf(ss.z) + EPS));
        o.w = -(dot.w / (sqrtf(ss.w) + EPS));
        ((float4*)(dist + (size_t)b * N))[n4] = o;
    }
}

// ---------------------------------------------------------------------------
// Kernel 3: fused write-softmax + memory update + read-dist.
// grid (4, BS), block 256, half-split over w. Mnew stored NON-TEMPORALLY so
// the 256MB write stream doesn't evict mem from L3 (mem was just read by
// k_wdist; its re-read here should be L3-hit). Raw dist_r -> ws buffer.
// ---------------------------------------------------------------------------
__global__ void __launch_bounds__(256, 2)
k_update(const float* __restrict__ mem, const float* __restrict__ wdist,
         const float* __restrict__ er, const float* __restrict__ wm,
         const float* __restrict__ knr,
         float* __restrict__ Mnew, float* __restrict__ dist_raw) {
    int b = blockIdx.y;
    int t = threadIdx.x;
    int lane = t & 63, wid = t >> 6;
    int half = t >> 7, c = t & 127;
    int n4 = blockIdx.x * 128 + c;
    __shared__ float se[W], sw[W];
    __shared__ float4 skT[W];
    __shared__ float red[4];
    __shared__ float4 pd0[128], pd1[128], pd2[128], pd3[128], pssv[128];
    se[t] = er[b * W + t];
    sw[t] = wm[b * W + t];
    const float* kb = knr + (size_t)b * R * W;
    skT[t] = make_float4(kb[t], kb[W + t], kb[2 * W + t], kb[3 * W + t]);

    // --- block-redundant softmax over the full raw dist row (2048) ---
    const float4* drow4 = (const float4*)(wdist + (size_t)b * N);
    float4 a0 = drow4[t];
    float4 a1 = drow4[256 + t];
    float mx = fmaxf(fmaxf(fmaxf(a0.x, a0.y), fmaxf(a0.z, a0.w)),
                     fmaxf(fmaxf(a1.x, a1.y), fmaxf(a1.z, a1.w)));
    mx = wave_max(mx);
    if (lane == 0) red[wid] = mx;
    __syncthreads();
    mx = fmaxf(fmaxf(red[0], red[1]), fmaxf(red[2], red[3]));
    __syncthreads();
    float sm = expf(a0.x - mx) + expf(a0.y - mx) + expf(a0.z - mx) + expf(a0.w - mx)
             + expf(a1.x - mx) + expf(a1.y - mx) + expf(a1.z - mx) + expf(a1.w - mx);
    sm = wave_sum(sm);
    if (lane == 0) red[wid] = sm;
    __syncthreads();
    sm = red[0] + red[1] + red[2] + red[3];
    float inv = 1.0f / sm;
    float4 dmine = drow4[n4];
    float4 wt;
    wt.x = expf(dmine.x - mx) * inv;
    wt.y = expf(dmine.y - mx) * inv;
    wt.z = expf(dmine.z - mx) * inv;
    wt.w = expf(dmine.w - mx) * inv;

    const float4* mb = (const float4*)(mem + (size_t)b * W * N) + n4;
    v4f* obv = (v4f*)(Mnew + (size_t)b * W * N) + n4;
    float4 ssv = make_float4(0.f, 0.f, 0.f, 0.f);
    float4 d0 = make_float4(0.f, 0.f, 0.f, 0.f);
    float4 d1 = make_float4(0.f, 0.f, 0.f, 0.f);
    float4 d2 = make_float4(0.f, 0.f, 0.f, 0.f);
    float4 d3 = make_float4(0.f, 0.f, 0.f, 0.f);
    int w0 = half * 128;
#pragma unroll 8
    for (int i = 0; i < 128; i++) {
        int w = w0 + i;
        float4 v = mb[(size_t)w * (N / 4)];
        float ew = se[w], mw = sw[w];
        float4 mn;
        mn.x = v.x + wt.x * (mw - v.x * ew);
        mn.y = v.y + wt.y * (mw - v.y * ew);
        mn.z = v.z + wt.z * (mw - v.z * ew);
        mn.w = v.w + wt.w * (mw - v.w * ew);
        v4f sv; sv[0] = mn.x; sv[1] = mn.y; sv[2] = mn.z; sv[3] = mn.w;
        __builtin_nontemporal_store(sv, obv + (size_t)w * (N / 4));
        ssv.x += mn.x * mn.x; ssv.y += mn.y * mn.y;
        ssv.z += mn.z * mn.z; ssv.w += mn.w * mn.w;
        float4 kv = skT[w];
        d0.x += kv.x * mn.x; d0.y += kv.x * mn.y; d0.z += kv.x * mn.z; d0.w += kv.x * mn.w;
        d1.x += kv.y * mn.x; d1.y += kv.y * mn.y; d1.z += kv.y * mn.z; d1.w += kv.y * mn.w;
        d2.x += kv.z * mn.x; d2.y += kv.z * mn.y; d2.z += kv.z * mn.z; d2.w += kv.z * mn.w;
        d3.x += kv.w * mn.x; d3.y += kv.w * mn.y; d3.z += kv.w * mn.z; d3.w += kv.w * mn.w;
    }
    if (half == 0) {
        pd0[c] = d0; pd1[c] = d1; pd2[c] = d2; pd3[c] = d3; pssv[c] = ssv;
    }
    __syncthreads();
    if (half == 1) {
        float4 q;
        q = pd0[c]; d0.x += q.x; d0.y += q.y; d0.z += q.z; d0.w += q.w;
        q = pd1[c]; d1.x += q.x; d1.y += q.y; d1.z += q.z; d1.w += q.w;
        q = pd2[c]; d2.x += q.x; d2.y += q.y; d2.z += q.z; d2.w += q.w;
        q = pd3[c]; d3.x += q.x; d3.y += q.y; d3.z += q.z; d3.w += q.w;
        q = pssv[c]; ssv.x += q.x; ssv.y += q.y; ssv.z += q.z; ssv.w += q.w;
        float4 ivn;
        ivn.x = 1.0f / (sqrtf(ssv.x) + EPS);
        ivn.y = 1.0f / (sqrtf(ssv.y) + EPS);
        ivn.z = 1.0f / (sqrtf(ssv.z) + EPS);
        ivn.w = 1.0f / (sqrtf(ssv.w) + EPS);
        float4* dr = (float4*)(dist_raw + (size_t)b * R * N);
        dr[0 * (N / 4) + n4] = make_float4(d0.x * ivn.x, d0.y * ivn.y, d0.z * ivn.z, d0.w * ivn.w);
        dr[1 * (N / 4) + n4] = make_float4(d1.x * ivn.x, d1.y * ivn.y, d1.z * ivn.z, d1.w * ivn.w);
        dr[2 * (N / 4) + n4] = make_float4(d2.x * ivn.x, d2.y * ivn.y, d2.z * ivn.z, d2.w * ivn.w);
        dr[3 * (N / 4) + n4] = make_float4(d3.x * ivn.x, d3.y * ivn.y, d3.z * ivn.z, d3.w * ivn.w);
    }
}

// ---------------------------------------------------------------------------
// Kernel 4: fused read-softmax + m_read.
// grid (4, BS), block 256 (4 waves). Each block: block-redundant softmax of
// the 4 raw dist_r rows (from ws) into LDS; block x==0 writes read_wt output.
// Then m_read accumulation with NON-TEMPORAL Mnew loads (stream, no reuse).
// ---------------------------------------------------------------------------
__global__ void __launch_bounds__(256, 2)
k_mread(const float* __restrict__ Mnew, const float* __restrict__ dist_raw,
        float* __restrict__ rwt_out, float* __restrict__ m_read) {
    int b = blockIdx.y;
    int w0 = blockIdx.x * 64;
    int t = threadIdx.x;
    int lane = t & 63, wid = t >> 6;

    __shared__ float rwt_s[R * N];  // 32 KB
    __shared__ float redm[16], reds[16];
    __shared__ float part[64][2][4];

    // --- softmax of 4 rows (block-redundant) ---
    const float4* drr = (const float4*)(dist_raw + (size_t)b * R * N);
    float4 a[R][2];
    float mxr[R], smr[R];
#pragma unroll
    for (int r = 0; r < R; r++) {
        a[r][0] = drr[r * 512 + t];
        a[r][1] = drr[r * 512 + 256 + t];
        float m0 = fmaxf(fmaxf(a[r][0].x, a[r][0].y), fmaxf(a[r][0].z, a[r][0].w));
        float m1 = fmaxf(fmaxf(a[r][1].x, a[r][1].y), fmaxf(a[r][1].z, a[r][1].w));
        float m = wave_max(fmaxf(m0, m1));
        if (lane == 0) redm[r * 4 + wid] = m;
    }
    __syncthreads();
#pragma unroll
    for (int r = 0; r < R; r++) {
        mxr[r] = fmaxf(fmaxf(redm[r * 4 + 0], redm[r * 4 + 1]),
                       fmaxf(redm[r * 4 + 2], redm[r * 4 + 3]));
        float4 e0, e1;
        e0.x = expf(a[r][0].x - mxr[r]); e0.y = expf(a[r][0].y - mxr[r]);
        e0.z = expf(a[r][0].z - mxr[r]); e0.w = expf(a[r][0].w - mxr[r]);
        e1.x = expf(a[r][1].x - mxr[r]); e1.y = expf(a[r][1].y - mxr[r]);
        e1.z = expf(a[r][1].z - mxr[r]); e1.w = expf(a[r][1].w - mxr[r]);
        a[r][0] = e0; a[r][1] = e1;
        float s = e0.x + e0.y + e0.z + e0.w + e1.x + e1.y + e1.z + e1.w;
        s = wave_sum(s);
        if (lane == 0) reds[r * 4 + wid] = s;
    }
    __syncthreads();
    float4* rs4 = (float4*)rwt_s;
#pragma unroll
    for (int r = 0; r < R; r++) {
        smr[r] = reds[r * 4 + 0] + reds[r * 4 + 1] + reds[r * 4 + 2] + reds[r * 4 + 3];
        float inv = 1.0f / smr[r];
        float4 o0, o1;
        o0.x = a[r][0].x * inv; o0.y = a[r][0].y * inv;
        o0.z = a[r][0].z * inv; o0.w = a[r][0].w * inv;
        o1.x = a[r][1].x * inv; o1.y = a[r][1].y * inv;
        o1.z = a[r][1].z * inv; o1.w = a[r][1].w * inv;
        rs4[r * 512 + t] = o0;
        rs4[r * 512 + 256 + t] = o1;
        if (blockIdx.x == 0) {
            float4* ro = (float4*)(rwt_out + (size_t)b * R * N);
            ro[r * 512 + t] = o0;
            ro[r * 512 + 256 + t] = o1;
        }
    }
    __syncthreads();

    // --- m_read accumulation ---
    int half = wid & 1, rowgrp = wid >> 1;
    int fbase = half * 256 + lane;

    float4 rw[R][4];
#pragma unroll
    for (int r = 0; r < R; r++)
#pragma unroll
        for (int k = 0; k < 4; k++) rw[r][k] = rs4[r * 512 + fbase + k * 64];

    const float* Mb = Mnew + (size_t)b * W * N;
#pragma unroll 4
    for (int wi = 0; wi < 32; wi++) {
        int wl = rowgrp * 32 + wi;
        const v4f* mrow = (const v4f*)(Mb + (size_t)(w0 + wl) * N);
        float4 v[4];
#pragma unroll
        for (int k = 0; k < 4; k++) {
            v4f vv = __builtin_nontemporal_load(mrow + fbase + k * 64);
            v[k].x = vv[0]; v[k].y = vv[1]; v[k].z = vv[2]; v[k].w = vv[3];
        }
        float a0 = 0.f, a1 = 0.f, a2 = 0.f, a3 = 0.f;
#pragma unroll
        for (int k = 0; k < 4; k++) {
            a0 += rw[0][k].x * v[k].x + rw[0][k].y * v[k].y + rw[0][k].z * v[k].z + rw[0][k].w * v[k].w;
            a1 += rw[1][k].x * v[k].x + rw[1][k].y * v[k].y + rw[1][k].z * v[k].z + rw[1][k].w * v[k].w;
            a2 += rw[2][k].x * v[k].x + rw[2][k].y * v[k].y + rw[2][k].z * v[k].z + rw[2][k].w * v[k].w;
            a3 += rw[3][k].x * v[k].x + rw[3][k].y * v[k].y + rw[3][k].z * v[k].z + rw[3][k].w * v[k].w;
        }
        a0 = wave_sum(a0);
        a1 = wave_sum(a1);
        a2 = wave_sum(a2);
        a3 = wave_sum(a3);
        if (lane == 0) {
            part[wl][half][0] = a0;
            part[wl][half][1] = a1;
            part[wl][half][2] = a2;
            part[wl][half][3] = a3;
        }
    }
    __syncthreads();
    int w = t >> 2, r = t & 3;
    float sres = part[w][0][r] + part[w][1][r];
    m_read[((size_t)b * R + r) * W + w0 + w] = sres;
}

extern "C" void kernel_launch(void* const* d_in, const int* in_sizes, int n_in,
                              void* d_out, int out_size, void* d_ws, size_t ws_size,
                              hipStream_t stream) {
    const float* k_r  = (const float*)d_in[0];
    const float* m_t  = (const float*)d_in[1];
    const float* e_t  = (const float*)d_in[2];
    const float* m_er = (const float*)d_in[3];
    const float* mem  = (const float*)d_in[4];
    const float* gW   = (const float*)d_in[5];
    const float* gb   = (const float*)d_in[6];
    const float* oW   = (const float*)d_in[7];
    const float* ob   = (const float*)d_in[8];

    float* out = (float*)d_out;
    // output layout: m_read (bs,R,W) | M_new (bs,W,N) | read_wt (bs,R,N)
    float* m_read = out;
    float* Mnew   = out + (size_t)BS * R * W;
    float* rwt    = out + (size_t)BS * R * W + (size_t)BS * W * N;

    float* ws  = (float*)d_ws;
    float* wm  = ws;                                              // BS*W
    float* er  = ws + (size_t)BS * W;                             // BS*W
    float* knw = ws + (size_t)2 * BS * W;                         // BS*W
    float* knr = ws + (size_t)3 * BS * W;                         // BS*R*W
    float* wdist = ws + (size_t)3 * BS * W + (size_t)BS * R * W;  // BS*N
    float* draw  = wdist + (size_t)BS * N;                        // BS*R*N raw read-dist

    k_prep<<<BS, 256, 0, stream>>>(k_r, m_t, e_t, m_er, gW, gb, oW, ob, wm, er, knw, knr);
    k_wdist<<<dim3(4, BS), 256, 0, stream>>>(mem, knw, wdist);
    k_update<<<dim3(4, BS), 256, 0, stream>>>(mem, wdist, er, wm, knr, Mnew, draw);
    k_mread<<<dim3(4, BS), 256, 0, stream>>>(Mnew, draw, rwt, m_read);
}